// Round 12
// baseline (117.976 us; speedup 1.0000x reference)
//
#include <hip/hip_runtime.h>
#include <hip/hip_bf16.h>

#define B_    4
#define CIN   64
#define E_    75000
#define K_    5
#define COUT  128
#define KTOT  320   // K_*CIN
#define MROWS 64    // rows per block (4 waves x 16)
#define NBLK  1172  // ceil(E_/MROWS)

typedef __attribute__((ext_vector_type(8))) short short8;
typedef __attribute__((ext_vector_type(4))) float f32x4;
typedef __attribute__((ext_vector_type(4))) unsigned int u32x4;

typedef __attribute__((address_space(1))) const void gas_void;
typedef __attribute__((address_space(3))) void las_void;

static __device__ __forceinline__ unsigned short f2bf(float f) {
    __hip_bfloat16 h = __float2bfloat16(f);
    union { __hip_bfloat16 h; unsigned short u; } cv; cv.h = h; return cv.u;
}
static __device__ __forceinline__ float bflo(unsigned int v) { return __uint_as_float(v << 16); }
static __device__ __forceinline__ float bfhi(unsigned int v) { return __uint_as_float(v & 0xffff0000u); }
// packed f32->bf16 RNE (1 VALU inst)
static __device__ __forceinline__ unsigned int cvtpk(float lo, float hi) {
    unsigned int r;
    asm("v_cvt_pk_bf16_f32 %0, %1, %2" : "=v"(r) : "v"(lo), "v"(hi));
    return r;
}

// ---------------- Kernel 1: x (B,CIN,E) f32 -> f (B,E,CIN) bf16 ----------------
__global__ __launch_bounds__(256) void transpose_kernel(const float* __restrict__ x,
                                                        unsigned short* __restrict__ f) {
    __shared__ float lds[64][65];
    const int b  = blockIdx.y;
    const int e0 = blockIdx.x * 64;
    const int tid = threadIdx.x;
    const int lane_e = tid & 63;
    const int cg = tid >> 6;
    const int egc = min(e0 + lane_e, E_ - 1);
    const float* xb = x + (size_t)b * CIN * E_;
#pragma unroll
    for (int i = 0; i < 16; ++i) {
        int c = cg * 16 + i;
        lds[lane_e][c] = __builtin_nontemporal_load(&xb[(size_t)c * E_ + egc]);
    }
    __syncthreads();
    const int e = tid >> 2;
    const int q = tid & 3;
    if (e0 + e < E_) {
        unsigned short tmp[16] __attribute__((aligned(16)));
#pragma unroll
        for (int i = 0; i < 16; ++i) tmp[i] = f2bf(lds[e][q * 16 + i]);
        unsigned short* dst = f + ((size_t)b * E_ + e0 + e) * CIN + q * 16;
        *(short8*)dst       = *(short8*)&tmp[0];
        *(short8*)(dst + 8) = *(short8*)&tmp[8];
    }
}

// ------- Kernel 2: W (COUT, KTOT) f32 -> fragment-ordered bf16 Wf -------
// frag t = (s*8 + nf)*64 + lane ; elem j = W[nf*16 + (lane&15)][s*32 + (lane>>4)*8 + j]
__global__ void wconv_kernel(const float* __restrict__ W, unsigned short* __restrict__ Wf) {
    int t = blockIdx.x * 256 + threadIdx.x;
    if (t >= 10 * 8 * 64) return;
    int lane = t & 63;
    int fidx = (t >> 6) & 7;
    int s    = t >> 9;
    int row = fidx * 16 + (lane & 15);
    int col = s * 32 + (lane >> 4) * 8;
    const float* src = W + (size_t)row * KTOT + col;
    unsigned short tmp[8] __attribute__((aligned(16)));
#pragma unroll
    for (int j = 0; j < 8; ++j) tmp[j] = f2bf(src[j]);
    *(short8*)(Wf + (size_t)t * 8) = *(short8*)tmp;
}

// ---------------- Kernel 3: chunked-K gather-fused MFMA GEMM ----------------
// 256 threads = 4 waves x 16 rows, LDS = 16 KB (2 K-steps of Wf). W is streamed
// through LDS in 5 chunks via global_load_lds DMA; barriers scope only 4 waves
// and short MFMA phases. 5 blocks/CU co-resident anti-phase the pipeline.
static __device__ __forceinline__ short8 ldfrag(const unsigned short* __restrict__ base,
                                                unsigned int off_shorts) {
    return *(const short8*)(base + off_shorts);
}

static __device__ __forceinline__ void mk_sumdiff(short8 xa, short8 xb, short8& s8, short8& d8) {
    union U { short8 s; unsigned int u[4]; } ua, ub, us, ud;
    ua.s = xa; ub.s = xb;
#pragma unroll
    for (int i = 0; i < 4; ++i) {
        float al = bflo(ua.u[i]), ah = bfhi(ua.u[i]);
        float bl = bflo(ub.u[i]), bh = bfhi(ub.u[i]);
        us.u[i] = cvtpk(al + bl, ah + bh);
        ud.u[i] = cvtpk(al - bl, ah - bh) & 0x7fff7fffu;
    }
    s8 = us.s; d8 = ud.s;
}

__global__ __launch_bounds__(256)
__attribute__((amdgpu_waves_per_eu(5, 5)))
void meshconv_kernel(
    const unsigned short* __restrict__ f, const int* __restrict__ em,
    const unsigned short* __restrict__ Wf, const float* __restrict__ bias,
    float* __restrict__ out) {
    __shared__ u32x4 Bs[1024];                   // 16 KB: one 2-step chunk of Wf

    const int tid  = threadIdx.x;
    const int w    = tid >> 6, lane = tid & 63;
    const int b    = blockIdx.y;
    const int e0w  = blockIdx.x * MROWS + w * 16;
    const int l15  = lane & 15, l4 = lane >> 4;
    const int er   = min(e0w + l15, E_ - 1);     // this lane's source row (clamped tail)

    const unsigned short* fb = f + (size_t)b * E_ * CIN;
    const u32x4* Wg = (const u32x4*)Wf;
    const int wbase = tid & ~63;                 // wave-uniform LDS slot base

    // ---- DMA chunk 0 of Wf -> LDS (fire-and-forget, no VGPRs) ----
#pragma unroll
    for (int i = 0; i < 4; ++i)
        __builtin_amdgcn_global_load_lds((gas_void*)(Wg + (i * 256 + tid)),
                                         (las_void*)(Bs + (i * 256 + wbase)), 16, 0, 0);

    // ---- neighbor indices (k=0 is self by construction) ----
    const int* emr = em + ((size_t)b * E_ + er) * K_;
    int i1 = emr[1], i2 = emr[2], i3 = emr[3], i4 = emr[4];

    // ---- all 10 raw-fragment gathers in flight ----
    const unsigned int co = (unsigned int)(l4 * 8);
    short8 gS0 = ldfrag(fb, ((unsigned int)er << 6) + co);
    short8 gS1 = ldfrag(fb, ((unsigned int)er << 6) + 32 + co);
    short8 g1a = ldfrag(fb, ((unsigned int)i1 << 6) + co);
    short8 g1b = ldfrag(fb, ((unsigned int)i1 << 6) + 32 + co);
    short8 g2a = ldfrag(fb, ((unsigned int)i2 << 6) + co);
    short8 g2b = ldfrag(fb, ((unsigned int)i2 << 6) + 32 + co);
    short8 g3a = ldfrag(fb, ((unsigned int)i3 << 6) + co);
    short8 g3b = ldfrag(fb, ((unsigned int)i3 << 6) + 32 + co);
    short8 g4a = ldfrag(fb, ((unsigned int)i4 << 6) + co);
    short8 g4b = ldfrag(fb, ((unsigned int)i4 << 6) + 32 + co);

    // ---- composite A fragments (vmcnt-waits on the gathers) ----
    short8 A[10];
    A[0] = gS0; A[1] = gS1;
    mk_sumdiff(g1a, g3a, A[2], A[6]);
    mk_sumdiff(g1b, g3b, A[3], A[7]);
    mk_sumdiff(g2a, g4a, A[4], A[8]);
    mk_sumdiff(g2b, g4b, A[5], A[9]);

    // ---- acc init = bias ----
    f32x4 acc[8];
#pragma unroll
    for (int nf = 0; nf < 8; ++nf) {
        float bv = bias[nf * 16 + l15];
        acc[nf] = (f32x4){bv, bv, bv, bv};
    }

    __syncthreads();                              // chunk 0 staged (drains gathers too)

    // ---- chunked GEMM: 5 chunks x (2 K-steps x 8 N-frags) ----
    const short8* Bl = (const short8*)Bs;
#pragma unroll
    for (int c = 0; c < 5; ++c) {
#pragma unroll
        for (int sl = 0; sl < 2; ++sl) {
            short8 a_ = A[c * 2 + sl];
#pragma unroll
            for (int nf = 0; nf < 8; ++nf) {
                short8 bfr = Bl[(sl * 8 + nf) * 64 + lane];
                acc[nf] = __builtin_amdgcn_mfma_f32_16x16x32_bf16(a_, bfr, acc[nf], 0, 0, 0);
            }
        }
        if (c < 4) {
            __syncthreads();                      // all reads of chunk c done
#pragma unroll
            for (int i = 0; i < 4; ++i)
                __builtin_amdgcn_global_load_lds(
                    (gas_void*)(Wg + ((c + 1) * 1024 + i * 256 + tid)),
                    (las_void*)(Bs + (i * 256 + wbase)), 16, 0, 0);
            __syncthreads();                      // chunk c+1 staged (vmcnt drained)
        }
    }

    // ---- epilogue: store; out (B, COUT, E). E%4==0 -> aligned f32x4 ----
    float* ob = out + (size_t)b * COUT * E_;
    const int erow = e0w + l4 * 4;
    if (erow < E_) {
#pragma unroll
        for (int nf = 0; nf < 8; ++nf) {
            int o = nf * 16 + l15;
            *(f32x4*)(ob + (size_t)o * E_ + erow) = acc[nf];
        }
    }
}

extern "C" void kernel_launch(void* const* d_in, const int* in_sizes, int n_in,
                              void* d_out, int out_size, void* d_ws, size_t ws_size,
                              hipStream_t stream) {
    const float* x    = (const float*)d_in[0];
    const int*   em   = (const int*)d_in[1];
    const float* W    = (const float*)d_in[2];
    const float* bias = (const float*)d_in[3];
    float* out = (float*)d_out;

    unsigned short* f  = (unsigned short*)d_ws;                 // B*E*64 bf16 = 38.4 MB
    unsigned short* Wf = f + (size_t)B_ * E_ * CIN;             // 80 KB fragment-ordered W

    dim3 gridT(1172, B_);
    transpose_kernel<<<gridT, 256, 0, stream>>>(x, f);
    wconv_kernel<<<20, 256, 0, stream>>>(W, Wf);
    dim3 gridM(NBLK, B_);
    meshconv_kernel<<<gridM, 256, 0, stream>>>(f, em, Wf, bias, out);
}

// Round 13
// 107.433 us; speedup vs baseline: 1.0981x; 1.0981x over previous
//
#include <hip/hip_runtime.h>
#include <hip/hip_bf16.h>

#define B_    4
#define CIN   64
#define E_    75000
#define K_    5
#define COUT  128
#define KTOT  320   // K_*CIN
#define MROWS 128   // mesh rows per block (8 waves x 16)
#define NBLK  586   // mesh blocks per batch = ceil(E_/MROWS)
#define TBLK  586   // transpose blocks per batch (128 e-cols each)
#define WBLK  10    // wconv blocks (512 thr -> 5120 fragment-threads)

typedef __attribute__((ext_vector_type(8))) short short8;
typedef __attribute__((ext_vector_type(4))) float f32x4;
typedef __attribute__((ext_vector_type(4))) unsigned int u32x4;

static __device__ __forceinline__ unsigned short f2bf(float f) {
    __hip_bfloat16 h = __float2bfloat16(f);
    union { __hip_bfloat16 h; unsigned short u; } cv; cv.h = h; return cv.u;
}
static __device__ __forceinline__ float bflo(unsigned int v) { return __uint_as_float(v << 16); }
static __device__ __forceinline__ float bfhi(unsigned int v) { return __uint_as_float(v & 0xffff0000u); }
static __device__ __forceinline__ unsigned int cvtpk(float lo, float hi) {
    unsigned int r;
    asm("v_cvt_pk_bf16_f32 %0, %1, %2" : "=v"(r) : "v"(lo), "v"(hi));
    return r;
}
static __device__ __forceinline__ short8 ldfrag(const unsigned short* __restrict__ base,
                                                unsigned int off_shorts) {
    return *(const short8*)(base + off_shorts);
}
static __device__ __forceinline__ void mk_sumdiff(short8 xa, short8 xb, short8& s8, short8& d8) {
    union U { short8 s; unsigned int u[4]; } ua, ub, us, ud;
    ua.s = xa; ub.s = xb;
#pragma unroll
    for (int i = 0; i < 4; ++i) {
        float al = bflo(ua.u[i]), ah = bfhi(ua.u[i]);
        float bl = bflo(ub.u[i]), bh = bfhi(ub.u[i]);
        us.u[i] = cvtpk(al + bl, ah + bh);
        ud.u[i] = cvtpk(al - bl, ah - bh) & 0x7fff7fffu;
    }
    s8 = us.s; d8 = ud.s;
}

// ---------------- fused kernel: three roles per launch ----------------
// blocks [0, nMesh)              : meshconv for batch bMesh (R8 structure, verbatim)
// blocks [nMesh, nMesh+nTrans)   : x->f bf16 transpose for batch bTrans (128 e each)
// blocks [nMesh+nTrans, +WBLK)   : W->Wf fragment pack (only when doW)
union SMu {
    u32x4 Bs[5120];            // 80 KB  (mesh: Wf tile)
    float tl[2][64][65];       // 33 KB  (transpose: two 64x64 tiles)
};

__global__ __launch_bounds__(512)
__attribute__((amdgpu_waves_per_eu(4, 4)))
void fused_kernel(const float* __restrict__ x, unsigned short* __restrict__ f,
                  const float* __restrict__ W, unsigned short* __restrict__ Wf,
                  const int* __restrict__ em, const float* __restrict__ bias,
                  float* __restrict__ out,
                  int bMesh, int bTrans, int nMesh, int nTrans, int doW) {
    __shared__ SMu sm;
    const int bx  = blockIdx.x;
    const int tid = threadIdx.x;

    if (bx < nMesh) {
        // ================= MESH ROLE (R8 verbatim) =================
        const int w    = tid >> 6, lane = tid & 63;
        const int b    = bMesh;
        const int e0w  = bx * MROWS + w * 16;
        const int l15  = lane & 15, l4 = lane >> 4;
        const int er   = min(e0w + l15, E_ - 1);

        const unsigned short* fb = (const unsigned short*)f + (size_t)b * E_ * CIN;

        const int* emr = em + ((size_t)b * E_ + er) * K_;
        int i1 = emr[1], i2 = emr[2], i3 = emr[3], i4 = emr[4];

        const u32x4* Wg = (const u32x4*)Wf;
#pragma unroll
        for (int i = 0; i < 10; ++i) sm.Bs[i * 512 + tid] = Wg[i * 512 + tid];

        const unsigned int co = (unsigned int)(l4 * 8);
        short8 gS0 = ldfrag(fb, ((unsigned int)er << 6) + co);
        short8 gS1 = ldfrag(fb, ((unsigned int)er << 6) + 32 + co);
        short8 g1a = ldfrag(fb, ((unsigned int)i1 << 6) + co);
        short8 g1b = ldfrag(fb, ((unsigned int)i1 << 6) + 32 + co);
        short8 g2a = ldfrag(fb, ((unsigned int)i2 << 6) + co);
        short8 g2b = ldfrag(fb, ((unsigned int)i2 << 6) + 32 + co);
        short8 g3a = ldfrag(fb, ((unsigned int)i3 << 6) + co);
        short8 g3b = ldfrag(fb, ((unsigned int)i3 << 6) + 32 + co);
        short8 g4a = ldfrag(fb, ((unsigned int)i4 << 6) + co);
        short8 g4b = ldfrag(fb, ((unsigned int)i4 << 6) + 32 + co);

        __syncthreads();

        short8 A[10];
        A[0] = gS0; A[1] = gS1;
        mk_sumdiff(g1a, g3a, A[2], A[6]);
        mk_sumdiff(g1b, g3b, A[3], A[7]);
        mk_sumdiff(g2a, g4a, A[4], A[8]);
        mk_sumdiff(g2b, g4b, A[5], A[9]);

        const short8* Bl = (const short8*)sm.Bs;
        f32x4 acc[8];
#pragma unroll
        for (int nf = 0; nf < 8; ++nf) acc[nf] = (f32x4){0.f, 0.f, 0.f, 0.f};

#pragma unroll
        for (int s = 0; s < 10; ++s) {
#pragma unroll
            for (int nf = 0; nf < 8; ++nf) {
                short8 bfr = Bl[(s * 8 + nf) * 64 + lane];
                acc[nf] = __builtin_amdgcn_mfma_f32_16x16x32_bf16(A[s], bfr, acc[nf], 0, 0, 0);
            }
        }

        float* ob = out + (size_t)b * COUT * E_;
        const int erow = e0w + l4 * 4;
        if (erow < E_) {
#pragma unroll
            for (int nf = 0; nf < 8; ++nf) {
                int o = nf * 16 + l15;
                f32x4 v = acc[nf] + bias[o];
                *(f32x4*)(ob + (size_t)o * E_ + erow) = v;
            }
        }
    } else if (bx < nMesh + nTrans) {
        // ================= TRANSPOSE ROLE (2 x 64-e tiles) =================
        const int tile = bx - nMesh;
        const int half = tid >> 8;               // 0,1
        const int t2   = tid & 255;
        const int b    = bTrans;
        const int e0   = tile * 128 + half * 64;
        const int lane_e = t2 & 63;
        const int cg     = t2 >> 6;
        const int egc = min(e0 + lane_e, E_ - 1);
        const float* xb = x + (size_t)b * CIN * E_;
        float (*lds)[65] = sm.tl[half];
#pragma unroll
        for (int i = 0; i < 16; ++i) {
            int c = cg * 16 + i;
            lds[lane_e][c] = __builtin_nontemporal_load(&xb[(size_t)c * E_ + egc]);
        }
        __syncthreads();
        const int e = t2 >> 2;
        const int q = t2 & 3;
        if (e0 + e < E_) {
            unsigned short tmp[16] __attribute__((aligned(16)));
#pragma unroll
            for (int i = 0; i < 16; ++i) tmp[i] = f2bf(lds[e][q * 16 + i]);
            unsigned short* dst = f + ((size_t)b * E_ + e0 + e) * CIN + q * 16;
            *(short8*)dst       = *(short8*)&tmp[0];
            *(short8*)(dst + 8) = *(short8*)&tmp[8];
        }
    } else if (doW) {
        // ================= WCONV ROLE =================
        int t = (bx - nMesh - nTrans) * 512 + tid;
        if (t < 10 * 8 * 64) {
            int lane = t & 63;
            int fidx = (t >> 6) & 7;
            int s    = t >> 9;
            int row = fidx * 16 + (lane & 15);
            int col = s * 32 + (lane >> 4) * 8;
            const float* src = W + (size_t)row * KTOT + col;
            unsigned short tmp[8] __attribute__((aligned(16)));
#pragma unroll
            for (int j = 0; j < 8; ++j) tmp[j] = f2bf(src[j]);
            *(short8*)(Wf + (size_t)t * 8) = *(short8*)tmp;
        }
    }
}

extern "C" void kernel_launch(void* const* d_in, const int* in_sizes, int n_in,
                              void* d_out, int out_size, void* d_ws, size_t ws_size,
                              hipStream_t stream) {
    const float* x    = (const float*)d_in[0];
    const int*   em   = (const int*)d_in[1];
    const float* W    = (const float*)d_in[2];
    const float* bias = (const float*)d_in[3];
    float* out = (float*)d_out;

    unsigned short* f  = (unsigned short*)d_ws;                 // B*E*64 bf16 = 38.4 MB
    unsigned short* Wf = f + (size_t)B_ * E_ * CIN;             // 80 KB fragment-ordered W

    // L1: transpose(b0) + wconv
    fused_kernel<<<TBLK + WBLK, 512, 0, stream>>>(x, f, W, Wf, em, bias, out,
                                                  0, 0, 0, TBLK, 1);
    // L2..L4: mesh(b) + transpose(b+1)
    for (int b = 0; b < B_ - 1; ++b)
        fused_kernel<<<NBLK + TBLK, 512, 0, stream>>>(x, f, W, Wf, em, bias, out,
                                                      b, b + 1, NBLK, TBLK, 0);
    // L5: mesh(b3)
    fused_kernel<<<NBLK, 512, 0, stream>>>(x, f, W, Wf, em, bias, out,
                                           B_ - 1, 0, NBLK, 0, 0);
}